// Round 5
// baseline (1940.273 us; speedup 1.0000x reference)
//
#include <hip/hip_runtime.h>

#define NCV 100000
#define NTV 300000
#define NPV 50000
#define DD 128
#define OUTC 10
#define EMV 300000
#define EIV 600000
#define NTOT (2 * NTV + NCV + NPV)      // 750000 concatenated count slots
#define TOTE (2 * (EMV + EIV))          // 1800000 pool entries

typedef unsigned short u16;
typedef unsigned int u32;

// ---------- bf16 storage helpers (intermediates only; I/O is fp32) ----------
__device__ __forceinline__ u16 f2bf(float f) {
  u32 x = __float_as_uint(f);
  return (u16)((x + 0x7fffu + ((x >> 16) & 1u)) >> 16);
}
__device__ __forceinline__ u32 pack2(float a, float b) {
  return (u32)f2bf(a) | ((u32)f2bf(b) << 16);
}
__device__ __forceinline__ void unpack8(uint4 q, float* v) {
  v[0] = __uint_as_float(q.x << 16); v[1] = __uint_as_float(q.x & 0xffff0000u);
  v[2] = __uint_as_float(q.y << 16); v[3] = __uint_as_float(q.y & 0xffff0000u);
  v[4] = __uint_as_float(q.z << 16); v[5] = __uint_as_float(q.z & 0xffff0000u);
  v[6] = __uint_as_float(q.w << 16); v[7] = __uint_as_float(q.w & 0xffff0000u);
}

// ---------------- embed: h[n, f*16+d] = x[n,f]*W[f,d] + b[f,d]  (fp32 in, bf16 out) ----------------
__global__ __launch_bounds__(256) void embed_kernel(
    const float* __restrict__ x, const float* __restrict__ Wc,
    const float* __restrict__ bc, u16* __restrict__ h, int n) {
  int idx = blockIdx.x * 256 + threadIdx.x;
  if (idx >= n * 8) return;
  int node = idx >> 3, f = idx & 7;
  float xv = x[idx];  // x[node*8+f]
  const float4* w4 = (const float4*)Wc + f * 4;  // 16 floats per column
  const float4* b4 = (const float4*)bc + f * 4;
  float r[16];
  #pragma unroll
  for (int q = 0; q < 4; ++q) {
    float4 w = w4[q], b = b4[q];
    r[q * 4 + 0] = xv * w.x + b.x;
    r[q * 4 + 1] = xv * w.y + b.y;
    r[q * 4 + 2] = xv * w.z + b.z;
    r[q * 4 + 3] = xv * w.w + b.w;
  }
  uint4 o0, o1;
  o0.x = pack2(r[0], r[1]);   o0.y = pack2(r[2], r[3]);
  o0.z = pack2(r[4], r[5]);   o0.w = pack2(r[6], r[7]);
  o1.x = pack2(r[8], r[9]);   o1.y = pack2(r[10], r[11]);
  o1.z = pack2(r[12], r[13]); o1.w = pack2(r[14], r[15]);
  uint4* hp = (uint4*)h + (size_t)node * 16 + f * 2;
  hp[0] = o0; hp[1] = o1;
}

// ---------------- CSR build ----------------
__global__ __launch_bounds__(256) void count_kernel(
    const int* __restrict__ idxs, int* __restrict__ cnt, int ne) {
  int e = blockIdx.x * 256 + threadIdx.x;
  if (e < ne) atomicAdd(&cnt[idxs[e]], 1);
}

__global__ __launch_bounds__(256) void scan1_kernel(
    const int* __restrict__ cnt, int* __restrict__ off,
    int* __restrict__ bsum, int n) {
  __shared__ int sd[256];
  int tid = threadIdx.x;
  int base = blockIdx.x * 1024 + tid * 4;
  int v0 = 0, v1 = 0, v2 = 0, v3 = 0;
  if (base + 0 < n) v0 = cnt[base + 0];
  if (base + 1 < n) v1 = cnt[base + 1];
  if (base + 2 < n) v2 = cnt[base + 2];
  if (base + 3 < n) v3 = cnt[base + 3];
  int tsum = v0 + v1 + v2 + v3;
  sd[tid] = tsum;
  __syncthreads();
  for (int o = 1; o < 256; o <<= 1) {
    int xv = 0;
    if (tid >= o) xv = sd[tid - o];
    __syncthreads();
    sd[tid] += xv;
    __syncthreads();
  }
  int ex = sd[tid] - tsum;
  if (base + 0 < n) off[base + 0] = ex;
  if (base + 1 < n) off[base + 1] = ex + v0;
  if (base + 2 < n) off[base + 2] = ex + v0 + v1;
  if (base + 3 < n) off[base + 3] = ex + v0 + v1 + v2;
  if (tid == 255) bsum[blockIdx.x] = sd[255];
}

__global__ __launch_bounds__(256) void scan2_kernel(int* __restrict__ bsum, int nb) {
  __shared__ int sd[256];
  int tid = threadIdx.x;
  int base = tid * 4;
  int v0 = 0, v1 = 0, v2 = 0, v3 = 0;
  if (base + 0 < nb) v0 = bsum[base + 0];
  if (base + 1 < nb) v1 = bsum[base + 1];
  if (base + 2 < nb) v2 = bsum[base + 2];
  if (base + 3 < nb) v3 = bsum[base + 3];
  int tsum = v0 + v1 + v2 + v3;
  sd[tid] = tsum;
  __syncthreads();
  for (int o = 1; o < 256; o <<= 1) {
    int xv = 0;
    if (tid >= o) xv = sd[tid - o];
    __syncthreads();
    sd[tid] += xv;
    __syncthreads();
  }
  int ex = sd[tid] - tsum;
  if (base + 0 < nb) bsum[base + 0] = ex;
  if (base + 1 < nb) bsum[base + 1] = ex + v0;
  if (base + 2 < nb) bsum[base + 2] = ex + v0 + v1;
  if (base + 3 < nb) bsum[base + 3] = ex + v0 + v1 + v2;
}

__global__ __launch_bounds__(256) void scan3_kernel(
    int* __restrict__ off, const int* __restrict__ bsum,
    int* __restrict__ cur, int n, int tote) {
  int i = blockIdx.x * 256 + threadIdx.x;
  if (i > n) return;
  int v = (i == n) ? tote : (off[i] + bsum[i >> 10]);
  off[i] = v;
  cur[i] = v;
}

__global__ __launch_bounds__(256) void fill_kernel(
    const int* __restrict__ dsti, const int* __restrict__ srci,
    int* __restrict__ cur, int* __restrict__ pool, int ne) {
  int e = blockIdx.x * 256 + threadIdx.x;
  if (e >= ne) return;
  int pos = atomicAdd(&cur[dsti[e]], 1);
  pool[pos] = srci[e];
}

// ---------------- staging helpers (h buffers are bf16) ----------------
#define GPAD 36
__device__ __forceinline__ void stage_own(
    const u16* __restrict__ h, int grow, bool rok, int srow, int scol,
    float (*tile)[GPAD]) {
  float v[16];
  if (rok) {
    const uint4* p = (const uint4*)h + (size_t)grow * 16 + scol * 2;
    unpack8(p[0], v);
    unpack8(p[1], v + 8);
  } else {
    #pragma unroll
    for (int i = 0; i < 16; ++i) v[i] = 0.f;
  }
  int k0 = scol * 16;
  #pragma unroll
  for (int i = 0; i < 16; ++i) tile[k0 + i][srow] = v[i];
}

__device__ __forceinline__ void stage_mean(
    const u16* __restrict__ hsrc, const int* __restrict__ off,
    const int* __restrict__ pool, int grow, bool rok, int srow, int scol,
    float (*tile)[GPAD]) {
  float a[16];
  #pragma unroll
  for (int i = 0; i < 16; ++i) a[i] = 0.f;
  int deg = 0, j0 = 0;
  if (rok) { j0 = off[grow]; deg = off[grow + 1] - j0; }
  for (int j = 0; j < deg; ++j) {
    int s = pool[j0 + j];
    const uint4* p = (const uint4*)hsrc + (size_t)s * 16 + scol * 2;
    float v[16];
    unpack8(p[0], v);
    unpack8(p[1], v + 8);
    #pragma unroll
    for (int i = 0; i < 16; ++i) a[i] += v[i];
  }
  float inv = 1.f / fmaxf((float)deg, 1.f);
  int k0 = scol * 16;
  #pragma unroll
  for (int i = 0; i < 16; ++i) tile[k0 + i][srow] = a[i] * inv;
}

// ---------------- SAGE, one relation: out = mean@Wn + own@Wr + b  (fp32 weights) ----------------
__global__ __launch_bounds__(256) void sage1_kernel(
    const u16* __restrict__ hown, const u16* __restrict__ hs1,
    const int* __restrict__ off1, const int* __restrict__ pool,
    const float* __restrict__ Wn1, const float* __restrict__ Wr1,
    const float* __restrict__ b1, u16* __restrict__ out, int n) {
  __shared__ float sm[DD][GPAD];
  __shared__ float sh[DD][GPAD];
  int tid = threadIdx.x;
  int row0 = blockIdx.x * 32;
  int srow = tid >> 3, scol = tid & 7;
  int grow = row0 + srow;
  bool rok = grow < n;
  stage_own(hown, grow, rok, srow, scol, sh);
  stage_mean(hs1, off1, pool, grow, rok, srow, scol, sm);
  __syncthreads();

  int c0 = (tid & 63) * 2;
  int ch = c0 >> 1;
  int rbase = (tid >> 6) * 8;
  float acc0[8], acc1[8];
  #pragma unroll
  for (int r = 0; r < 8; ++r) { acc0[r] = 0.f; acc1[r] = 0.f; }
  #pragma unroll 4
  for (int k = 0; k < DD; ++k) {
    float2 wn = *(const float2*)&Wn1[k * DD + c0];
    float2 wr = *(const float2*)&Wr1[k * DD + c0];
    float4 ma = *(const float4*)&sm[k][rbase];
    float4 mb = *(const float4*)&sm[k][rbase + 4];
    float4 ha = *(const float4*)&sh[k][rbase];
    float4 hb = *(const float4*)&sh[k][rbase + 4];
    acc0[0] += ma.x * wn.x + ha.x * wr.x;  acc1[0] += ma.x * wn.y + ha.x * wr.y;
    acc0[1] += ma.y * wn.x + ha.y * wr.x;  acc1[1] += ma.y * wn.y + ha.y * wr.y;
    acc0[2] += ma.z * wn.x + ha.z * wr.x;  acc1[2] += ma.z * wn.y + ha.z * wr.y;
    acc0[3] += ma.w * wn.x + ha.w * wr.x;  acc1[3] += ma.w * wn.y + ha.w * wr.y;
    acc0[4] += mb.x * wn.x + hb.x * wr.x;  acc1[4] += mb.x * wn.y + hb.x * wr.y;
    acc0[5] += mb.y * wn.x + hb.y * wr.x;  acc1[5] += mb.y * wn.y + hb.y * wr.y;
    acc0[6] += mb.z * wn.x + hb.z * wr.x;  acc1[6] += mb.z * wn.y + hb.z * wr.y;
    acc0[7] += mb.w * wn.x + hb.w * wr.x;  acc1[7] += mb.w * wn.y + hb.w * wr.y;
  }
  float bb0 = b1[c0];
  float bb1 = b1[c0 + 1];
  u32* o32 = (u32*)out;
  #pragma unroll
  for (int r = 0; r < 8; ++r) {
    int rr = row0 + rbase + r;
    if (rr < n) o32[(size_t)rr * 64 + ch] = pack2(acc0[r] + bb0, acc1[r] + bb1);
  }
}

// ---------------- SAGE, two relations fused (transaction):
// out = alpha*( mean1@Wn1 + mean2@Wn2 + own@(Wr1+Wr2) + b1 + b2 ) ----------------
__global__ __launch_bounds__(256) void sage2_kernel(
    const u16* __restrict__ hown,
    const u16* __restrict__ hs1, const int* __restrict__ off1,
    const u16* __restrict__ hs2, const int* __restrict__ off2,
    const int* __restrict__ pool,
    const float* __restrict__ Wn1, const float* __restrict__ Wr1, const float* __restrict__ b1,
    const float* __restrict__ Wn2, const float* __restrict__ Wr2, const float* __restrict__ b2,
    u16* __restrict__ out, int n, float alpha) {
  __shared__ float sm1[DD][GPAD];
  __shared__ float sm2[DD][GPAD];
  __shared__ float sh[DD][GPAD];
  int tid = threadIdx.x;
  int row0 = blockIdx.x * 32;
  int srow = tid >> 3, scol = tid & 7;
  int grow = row0 + srow;
  bool rok = grow < n;
  stage_own(hown, grow, rok, srow, scol, sh);
  stage_mean(hs1, off1, pool, grow, rok, srow, scol, sm1);
  stage_mean(hs2, off2, pool, grow, rok, srow, scol, sm2);
  __syncthreads();

  int c0 = (tid & 63) * 2;
  int ch = c0 >> 1;
  int rbase = (tid >> 6) * 8;
  float acc0[8], acc1[8];
  #pragma unroll
  for (int r = 0; r < 8; ++r) { acc0[r] = 0.f; acc1[r] = 0.f; }
  #pragma unroll 2
  for (int k = 0; k < DD; ++k) {
    float2 w1 = *(const float2*)&Wn1[k * DD + c0];
    float2 w2 = *(const float2*)&Wn2[k * DD + c0];
    float2 ra = *(const float2*)&Wr1[k * DD + c0];
    float2 rb = *(const float2*)&Wr2[k * DD + c0];
    float2 wr; wr.x = ra.x + rb.x; wr.y = ra.y + rb.y;
    float4 ma = *(const float4*)&sm1[k][rbase];
    float4 mb = *(const float4*)&sm1[k][rbase + 4];
    float4 pa = *(const float4*)&sm2[k][rbase];
    float4 pb = *(const float4*)&sm2[k][rbase + 4];
    float4 ha = *(const float4*)&sh[k][rbase];
    float4 hb = *(const float4*)&sh[k][rbase + 4];
    acc0[0] += ma.x * w1.x + pa.x * w2.x + ha.x * wr.x;
    acc1[0] += ma.x * w1.y + pa.x * w2.y + ha.x * wr.y;
    acc0[1] += ma.y * w1.x + pa.y * w2.x + ha.y * wr.x;
    acc1[1] += ma.y * w1.y + pa.y * w2.y + ha.y * wr.y;
    acc0[2] += ma.z * w1.x + pa.z * w2.x + ha.z * wr.x;
    acc1[2] += ma.z * w1.y + pa.z * w2.y + ha.z * wr.y;
    acc0[3] += ma.w * w1.x + pa.w * w2.x + ha.w * wr.x;
    acc1[3] += ma.w * w1.y + pa.w * w2.y + ha.w * wr.y;
    acc0[4] += mb.x * w1.x + pb.x * w2.x + hb.x * wr.x;
    acc1[4] += mb.x * w1.y + pb.x * w2.y + hb.x * wr.y;
    acc0[5] += mb.y * w1.x + pb.y * w2.x + hb.y * wr.x;
    acc1[5] += mb.y * w1.y + pb.y * w2.y + hb.y * wr.y;
    acc0[6] += mb.z * w1.x + pb.z * w2.x + hb.z * wr.x;
    acc1[6] += mb.z * w1.y + pb.z * w2.y + hb.z * wr.y;
    acc0[7] += mb.w * w1.x + pb.w * w2.x + hb.w * wr.x;
    acc1[7] += mb.w * w1.y + pb.w * w2.y + hb.w * wr.y;
  }
  float bb0 = b1[c0] + b2[c0];
  float bb1 = b1[c0 + 1] + b2[c0 + 1];
  u32* o32 = (u32*)out;
  #pragma unroll
  for (int r = 0; r < 8; ++r) {
    int rr = row0 + rbase + r;
    if (rr < n)
      o32[(size_t)rr * 64 + ch] =
          pack2(alpha * (acc0[r] + bb0), alpha * (acc1[r] + bb1));
  }
}

// ---------------- head: softmax(h @ W_out + b_out) -> fp32 out ----------------
__global__ __launch_bounds__(256) void out_softmax(
    const u16* __restrict__ h, const float* __restrict__ Wout,
    const float* __restrict__ bout, float* __restrict__ out, int n) {
  __shared__ float sw[DD * OUTC];
  __shared__ float sb[OUTC];
  int tid = threadIdx.x;
  for (int i = tid; i < DD * OUTC; i += 256) sw[i] = Wout[i];
  if (tid < OUTC) sb[tid] = bout[tid];
  __syncthreads();
  int row = blockIdx.x * 256 + tid;
  if (row >= n) return;
  float logit[OUTC];
  #pragma unroll
  for (int o = 0; o < OUTC; ++o) logit[o] = sb[o];
  const uint4* hp = (const uint4*)h + (size_t)row * 16;
  for (int k = 0; k < DD; k += 8) {
    float v[8];
    unpack8(hp[k >> 3], v);
    #pragma unroll
    for (int j = 0; j < 8; ++j) {
      #pragma unroll
      for (int o = 0; o < OUTC; ++o) logit[o] += v[j] * sw[(k + j) * OUTC + o];
    }
  }
  float m = logit[0];
  #pragma unroll
  for (int o = 1; o < OUTC; ++o) m = fmaxf(m, logit[o]);
  float s = 0.f;
  #pragma unroll
  for (int o = 0; o < OUTC; ++o) { logit[o] = __expf(logit[o] - m); s += logit[o]; }
  float invs = 1.0f / s;
  #pragma unroll
  for (int o = 0; o < OUTC; ++o) out[(size_t)row * OUTC + o] = logit[o] * invs;
}

extern "C" void kernel_launch(void* const* d_in, const int* in_sizes, int n_in,
                              void* d_out, int out_size, void* d_ws, size_t ws_size,
                              hipStream_t stream) {
  const float* x_c   = (const float*)d_in[0];
  const float* x_t   = (const float*)d_in[1];
  const float* x_p   = (const float*)d_in[2];
  const float* W_col = (const float*)d_in[3];
  const float* b_col = (const float*)d_in[4];
  const float* Wn    = (const float*)d_in[5];
  const float* Wr    = (const float*)d_in[6];
  const float* b_lin = (const float*)d_in[7];
  const float* W_out = (const float*)d_in[8];
  const float* b_out = (const float*)d_in[9];
  const int* e_m_src = (const int*)d_in[10];
  const int* e_m_dst = (const int*)d_in[11];
  const int* e_i_src = (const int*)d_in[12];
  const int* e_i_dst = (const int*)d_in[13];
  float* out = (float*)d_out;

  // ---- workspace carve-out (~170 MB), 256B-aligned regions ----
  size_t cursor = 0;
  char* base = (char*)d_ws;
  auto alloc = [&](size_t bytes) {
    void* p = base + cursor;
    cursor += (bytes + 255) & ~(size_t)255;
    return p;
  };
  u16* h_t  = (u16*)alloc((size_t)NTV * DD * 2);
  u16* h_cA = (u16*)alloc((size_t)NCV * DD * 2);
  u16* h_cB = (u16*)alloc((size_t)NCV * DD * 2);
  u16* h_pA = (u16*)alloc((size_t)NPV * DD * 2);
  u16* h_pB = (u16*)alloc((size_t)NPV * DD * 2);
  int* pool = (int*)alloc((size_t)TOTE * 4);
  int* cnt  = (int*)alloc((size_t)NTOT * 4);
  int* off  = (int*)alloc((size_t)(NTOT + 1) * 4);
  int* cur  = (int*)alloc((size_t)(NTOT + 1) * 4);
  int* bsum = (int*)alloc(1024 * 4);

  // CSR segment bases: seg0 [0,NT): t<-c (makes); seg1 [NT,2NT): t<-p (in);
  // seg2 [2NT,2NT+NC): c<-t (makes); seg3: p<-t (in).
  const int S0 = 0, S1 = NTV, S2 = 2 * NTV, S3 = 2 * NTV + NCV;

  const float* Wn_l[2][4]; const float* Wr_l[2][4]; const float* b_l[2][4];
  for (int l = 0; l < 2; ++l)
    for (int r = 0; r < 4; ++r) {
      Wn_l[l][r] = Wn + (size_t)(l * 4 + r) * DD * DD;
      Wr_l[l][r] = Wr + (size_t)(l * 4 + r) * DD * DD;
      b_l[l][r]  = b_lin + (size_t)(l * 4 + r) * DD;
    }

  int gEM = (EMV + 255) / 256, gEI = (EIV + 255) / 256;

  // ---- CSR build ----
  hipMemsetAsync(cnt, 0, (size_t)NTOT * 4, stream);
  count_kernel<<<gEM, 256, 0, stream>>>(e_m_dst, cnt + S0, EMV);
  count_kernel<<<gEI, 256, 0, stream>>>(e_i_dst, cnt + S1, EIV);
  count_kernel<<<gEM, 256, 0, stream>>>(e_m_src, cnt + S2, EMV);
  count_kernel<<<gEI, 256, 0, stream>>>(e_i_src, cnt + S3, EIV);
  int nblk = (NTOT + 1023) / 1024;  // 733
  scan1_kernel<<<nblk, 256, 0, stream>>>(cnt, off, bsum, NTOT);
  scan2_kernel<<<1, 256, 0, stream>>>(bsum, nblk);
  scan3_kernel<<<(NTOT + 1 + 255) / 256, 256, 0, stream>>>(off, bsum, cur, NTOT, TOTE);
  fill_kernel<<<gEM, 256, 0, stream>>>(e_m_dst, e_m_src, cur + S0, pool, EMV);
  fill_kernel<<<gEI, 256, 0, stream>>>(e_i_dst, e_i_src, cur + S1, pool, EIV);
  fill_kernel<<<gEM, 256, 0, stream>>>(e_m_src, e_m_dst, cur + S2, pool, EMV);
  fill_kernel<<<gEI, 256, 0, stream>>>(e_i_src, e_i_dst, cur + S3, pool, EIV);

  // ---- embeds ----
  embed_kernel<<<(NCV * 8 + 255) / 256, 256, 0, stream>>>(
      x_c, W_col + 0 * DD, b_col + 0 * DD, h_cA, NCV);
  embed_kernel<<<(NTV * 8 + 255) / 256, 256, 0, stream>>>(
      x_t, W_col + 1 * DD, b_col + 1 * DD, h_t, NTV);
  embed_kernel<<<(NPV * 8 + 255) / 256, 256, 0, stream>>>(
      x_p, W_col + 2 * DD, b_col + 2 * DD, h_pA, NPV);

  int gT = NTV / 32, gC = NCV / 32, gP = (NPV + 31) / 32;

  // ---- layer 0 ----
  sage1_kernel<<<gC, 256, 0, stream>>>(h_cA, h_t, off + S2, pool,
                                       Wn_l[0][1], Wr_l[0][1], b_l[0][1], h_cB, NCV);
  sage1_kernel<<<gP, 256, 0, stream>>>(h_pA, h_t, off + S3, pool,
                                       Wn_l[0][3], Wr_l[0][3], b_l[0][3], h_pB, NPV);
  sage2_kernel<<<gT, 256, 0, stream>>>(h_t, h_cA, off + S0, h_pA, off + S1, pool,
                                       Wn_l[0][0], Wr_l[0][0], b_l[0][0],
                                       Wn_l[0][2], Wr_l[0][2], b_l[0][2],
                                       h_t, NTV, 0.5f);
  // ---- layer 1 (only h_t live downstream) ----
  sage2_kernel<<<gT, 256, 0, stream>>>(h_t, h_cB, off + S0, h_pB, off + S1, pool,
                                       Wn_l[1][0], Wr_l[1][0], b_l[1][0],
                                       Wn_l[1][2], Wr_l[1][2], b_l[1][2],
                                       h_t, NTV, 0.5f);

  // ---- head ----
  out_softmax<<<(NTV + 255) / 256, 256, 0, stream>>>(h_t, W_out, b_out, out, NTV);
}

// Round 6
// 1017.545 us; speedup vs baseline: 1.9068x; 1.9068x over previous
//
#include <hip/hip_runtime.h>

#define NCV 100000
#define NTV 300000
#define NPV 50000
#define DD 128
#define OUTC 10
#define EMV 300000
#define EIV 600000
#define NTOT (2 * NTV + NCV + NPV)      // 750000 concatenated count slots
#define TOTE (2 * (EMV + EIV))          // 1800000 pool entries

typedef unsigned short u16;
typedef unsigned int u32;
typedef __attribute__((ext_vector_type(8))) short short8;   // 8 bf16 (4 VGPRs)
typedef __attribute__((ext_vector_type(4))) float floatx4;  // MFMA accumulator

union U4S8 { uint4 u; short8 s; };

// ---------- bf16 storage helpers (intermediates only; I/O is fp32) ----------
__device__ __forceinline__ u16 f2bf(float f) {
  u32 x = __float_as_uint(f);
  return (u16)((x + 0x7fffu + ((x >> 16) & 1u)) >> 16);
}
__device__ __forceinline__ u32 pack2(float a, float b) {
  return (u32)f2bf(a) | ((u32)f2bf(b) << 16);
}
__device__ __forceinline__ void unpack8(uint4 q, float* v) {
  v[0] = __uint_as_float(q.x << 16); v[1] = __uint_as_float(q.x & 0xffff0000u);
  v[2] = __uint_as_float(q.y << 16); v[3] = __uint_as_float(q.y & 0xffff0000u);
  v[4] = __uint_as_float(q.z << 16); v[5] = __uint_as_float(q.z & 0xffff0000u);
  v[6] = __uint_as_float(q.w << 16); v[7] = __uint_as_float(q.w & 0xffff0000u);
}

// ---------------- embed: h[n, f*16+d] = x[n,f]*W[f,d] + b[f,d]  (fp32 in, bf16 out) ----------------
__global__ __launch_bounds__(256) void embed_kernel(
    const float* __restrict__ x, const float* __restrict__ Wc,
    const float* __restrict__ bc, u16* __restrict__ h, int n) {
  int idx = blockIdx.x * 256 + threadIdx.x;
  if (idx >= n * 8) return;
  int node = idx >> 3, f = idx & 7;
  float xv = x[idx];
  const float4* w4 = (const float4*)Wc + f * 4;
  const float4* b4 = (const float4*)bc + f * 4;
  float r[16];
  #pragma unroll
  for (int q = 0; q < 4; ++q) {
    float4 w = w4[q], b = b4[q];
    r[q * 4 + 0] = xv * w.x + b.x;
    r[q * 4 + 1] = xv * w.y + b.y;
    r[q * 4 + 2] = xv * w.z + b.z;
    r[q * 4 + 3] = xv * w.w + b.w;
  }
  uint4 o0, o1;
  o0.x = pack2(r[0], r[1]);   o0.y = pack2(r[2], r[3]);
  o0.z = pack2(r[4], r[5]);   o0.w = pack2(r[6], r[7]);
  o1.x = pack2(r[8], r[9]);   o1.y = pack2(r[10], r[11]);
  o1.z = pack2(r[12], r[13]); o1.w = pack2(r[14], r[15]);
  uint4* hp = (uint4*)h + (size_t)node * 16 + f * 2;
  hp[0] = o0; hp[1] = o1;
}

// ---------------- weight prep: WB[n][k] bf16 (B-operand layout), bias fp32 ----------------
__global__ __launch_bounds__(256) void prep_w2(
    const float* __restrict__ Wn0, const float* __restrict__ Wn2,
    const float* __restrict__ Wr0, const float* __restrict__ Wr2,
    const float* __restrict__ b0, const float* __restrict__ b2,
    u16* __restrict__ WB, float* __restrict__ bt) {
  int i = blockIdx.x * 256 + threadIdx.x;
  if (i >= 128 * 384) return;
  int nn = i / 384, k = i % 384;
  float v;
  if (k < 128) v = Wn0[k * 128 + nn];
  else if (k < 256) v = Wn2[(k - 128) * 128 + nn];
  else v = Wr0[(k - 256) * 128 + nn] + Wr2[(k - 256) * 128 + nn];
  WB[i] = f2bf(v);
  if (i < 128) bt[i] = b0[i] + b2[i];
}

__global__ __launch_bounds__(256) void prep_w1(
    const float* __restrict__ Wn, const float* __restrict__ Wr,
    const float* __restrict__ b, u16* __restrict__ WB, float* __restrict__ bt) {
  int i = blockIdx.x * 256 + threadIdx.x;
  if (i >= 128 * 256) return;
  int nn = i / 256, k = i % 256;
  float v = (k < 128) ? Wn[k * 128 + nn] : Wr[(k - 128) * 128 + nn];
  WB[i] = f2bf(v);
  if (i < 128) bt[i] = b[i];
}

// ---------------- CSR build ----------------
__global__ __launch_bounds__(256) void count_kernel(
    const int* __restrict__ idxs, int* __restrict__ cnt, int ne) {
  int e = blockIdx.x * 256 + threadIdx.x;
  if (e < ne) atomicAdd(&cnt[idxs[e]], 1);
}

__global__ __launch_bounds__(256) void scan1_kernel(
    const int* __restrict__ cnt, int* __restrict__ off,
    int* __restrict__ bsum, int n) {
  __shared__ int sd[256];
  int tid = threadIdx.x;
  int base = blockIdx.x * 1024 + tid * 4;
  int v0 = 0, v1 = 0, v2 = 0, v3 = 0;
  if (base + 0 < n) v0 = cnt[base + 0];
  if (base + 1 < n) v1 = cnt[base + 1];
  if (base + 2 < n) v2 = cnt[base + 2];
  if (base + 3 < n) v3 = cnt[base + 3];
  int tsum = v0 + v1 + v2 + v3;
  sd[tid] = tsum;
  __syncthreads();
  for (int o = 1; o < 256; o <<= 1) {
    int xv = 0;
    if (tid >= o) xv = sd[tid - o];
    __syncthreads();
    sd[tid] += xv;
    __syncthreads();
  }
  int ex = sd[tid] - tsum;
  if (base + 0 < n) off[base + 0] = ex;
  if (base + 1 < n) off[base + 1] = ex + v0;
  if (base + 2 < n) off[base + 2] = ex + v0 + v1;
  if (base + 3 < n) off[base + 3] = ex + v0 + v1 + v2;
  if (tid == 255) bsum[blockIdx.x] = sd[255];
}

__global__ __launch_bounds__(256) void scan2_kernel(int* __restrict__ bsum, int nb) {
  __shared__ int sd[256];
  int tid = threadIdx.x;
  int base = tid * 4;
  int v0 = 0, v1 = 0, v2 = 0, v3 = 0;
  if (base + 0 < nb) v0 = bsum[base + 0];
  if (base + 1 < nb) v1 = bsum[base + 1];
  if (base + 2 < nb) v2 = bsum[base + 2];
  if (base + 3 < nb) v3 = bsum[base + 3];
  int tsum = v0 + v1 + v2 + v3;
  sd[tid] = tsum;
  __syncthreads();
  for (int o = 1; o < 256; o <<= 1) {
    int xv = 0;
    if (tid >= o) xv = sd[tid - o];
    __syncthreads();
    sd[tid] += xv;
    __syncthreads();
  }
  int ex = sd[tid] - tsum;
  if (base + 0 < nb) bsum[base + 0] = ex;
  if (base + 1 < nb) bsum[base + 1] = ex + v0;
  if (base + 2 < nb) bsum[base + 2] = ex + v0 + v1;
  if (base + 3 < nb) bsum[base + 3] = ex + v0 + v1 + v2;
}

__global__ __launch_bounds__(256) void scan3_kernel(
    int* __restrict__ off, const int* __restrict__ bsum,
    int* __restrict__ cur, int n, int tote) {
  int i = blockIdx.x * 256 + threadIdx.x;
  if (i > n) return;
  int v = (i == n) ? tote : (off[i] + bsum[i >> 10]);
  off[i] = v;
  cur[i] = v;
}

__global__ __launch_bounds__(256) void fill_kernel(
    const int* __restrict__ dsti, const int* __restrict__ srci,
    int* __restrict__ cur, int* __restrict__ pool, int ne) {
  int e = blockIdx.x * 256 + threadIdx.x;
  if (e >= ne) return;
  int pos = atomicAdd(&cur[dsti[e]], 1);
  pool[pos] = srci[e];
}

// ---------------- fused SAGE via MFMA ----------------
// out[32 x 128] = A[32 x KD] @ WB[KD x 128]^(stored as WB[n][k]) ; KD=(NSEG+1)*128
// A = [mean_1 | (mean_2) | own] staged in LDS row-major bf16, stride KD+8
// (odd 16B-quad stride => conflict-free b128 writes, A-frag reads)
template <int NSEG>
__global__ __launch_bounds__(256) void sage_mfma(
    const u16* __restrict__ hown,
    const u16* __restrict__ hs1, const int* __restrict__ off1,
    const u16* __restrict__ hs2, const int* __restrict__ off2,
    const int* __restrict__ pool,
    const u16* __restrict__ WB, const float* __restrict__ bt,
    u16* __restrict__ out, int n, float alpha) {
  constexpr int KD = (NSEG + 1) * 128;
  constexpr int ST = KD + 8;  // u16 units
  __shared__ u16 At[32 * ST];
  int tid = threadIdx.x;
  int row0 = blockIdx.x * 32;
  int row = tid >> 3, chunk = tid & 7;  // 8 threads/row, 32B chunks
  int grow = row0 + row;
  bool rok = grow < n;

  // own segment: raw 32B bf16 copy
  {
    uint4 a0 = make_uint4(0, 0, 0, 0), a1 = a0;
    if (rok) {
      const uint4* p = (const uint4*)hown + (size_t)grow * 16 + chunk * 2;
      a0 = p[0]; a1 = p[1];
    }
    uint4* d = (uint4*)&At[row * ST + NSEG * 128 + chunk * 16];
    d[0] = a0; d[1] = a1;
  }
  // mean segments: gather + fp32 accumulate + bf16 pack
  const u16* hsrc[2] = {hs1, hs2};
  const int* offs[2] = {off1, off2};
  #pragma unroll
  for (int sgi = 0; sgi < NSEG; ++sgi) {
    float a[16];
    #pragma unroll
    for (int i = 0; i < 16; ++i) a[i] = 0.f;
    int deg = 0, j0 = 0;
    if (rok) { j0 = offs[sgi][grow]; deg = offs[sgi][grow + 1] - j0; }
    const uint4* hb = (const uint4*)hsrc[sgi];
    for (int j = 0; j < deg; ++j) {
      int s = pool[j0 + j];
      const uint4* p = hb + (size_t)s * 16 + chunk * 2;
      uint4 q0 = p[0], q1 = p[1];
      float v[16];
      unpack8(q0, v); unpack8(q1, v + 8);
      #pragma unroll
      for (int i = 0; i < 16; ++i) a[i] += v[i];
    }
    float inv = 1.f / fmaxf((float)deg, 1.f);
    uint4 o0, o1;
    o0.x = pack2(a[0] * inv, a[1] * inv);   o0.y = pack2(a[2] * inv, a[3] * inv);
    o0.z = pack2(a[4] * inv, a[5] * inv);   o0.w = pack2(a[6] * inv, a[7] * inv);
    o1.x = pack2(a[8] * inv, a[9] * inv);   o1.y = pack2(a[10] * inv, a[11] * inv);
    o1.z = pack2(a[12] * inv, a[13] * inv); o1.w = pack2(a[14] * inv, a[15] * inv);
    uint4* d = (uint4*)&At[row * ST + sgi * 128 + chunk * 16];
    d[0] = o0; d[1] = o1;
  }
  __syncthreads();

  // MFMA: wave w -> rowtile (w&1), col group 64*(w>>1), 4 coltiles of 16
  int w = tid >> 6, lane = tid & 63;
  int m16 = lane & 15, quad = lane >> 4;
  int rb = (w & 1) * 16;
  int cg = (w >> 1) * 64;
  floatx4 acc[4];
  #pragma unroll
  for (int t = 0; t < 4; ++t) acc[t] = (floatx4){0.f, 0.f, 0.f, 0.f};
  const u16* arow = &At[(rb + m16) * ST + quad * 8];
  const u16* brow = &WB[(size_t)(cg + m16) * KD + quad * 8];
  #pragma unroll 2
  for (int ks = 0; ks < KD / 32; ++ks) {
    U4S8 av; av.u = *(const uint4*)(arow + ks * 32);
    #pragma unroll
    for (int t = 0; t < 4; ++t) {
      U4S8 bv; bv.u = *(const uint4*)(brow + (size_t)t * 16 * KD + ks * 32);
      acc[t] = __builtin_amdgcn_mfma_f32_16x16x32_bf16(av.s, bv.s, acc[t], 0, 0, 0);
    }
  }
  // epilogue: D col = lane&15, row = quad*4 + reg
  #pragma unroll
  for (int t = 0; t < 4; ++t) {
    int col = cg + t * 16 + m16;
    float bb = bt[col];
    #pragma unroll
    for (int r = 0; r < 4; ++r) {
      int rr = row0 + rb + quad * 4 + r;
      if (rr < n) out[(size_t)rr * 128 + col] = f2bf(alpha * (acc[t][r] + bb));
    }
  }
}

// ---------------- head: softmax(h @ W_out + b_out) -> fp32 out ----------------
__global__ __launch_bounds__(256) void out_softmax(
    const u16* __restrict__ h, const float* __restrict__ Wout,
    const float* __restrict__ bout, float* __restrict__ out, int n) {
  __shared__ float sw[DD * OUTC];
  __shared__ float sb[OUTC];
  int tid = threadIdx.x;
  for (int i = tid; i < DD * OUTC; i += 256) sw[i] = Wout[i];
  if (tid < OUTC) sb[tid] = bout[tid];
  __syncthreads();
  int row = blockIdx.x * 256 + tid;
  if (row >= n) return;
  float logit[OUTC];
  #pragma unroll
  for (int o = 0; o < OUTC; ++o) logit[o] = sb[o];
  const uint4* hp = (const uint4*)h + (size_t)row * 16;
  for (int k = 0; k < DD; k += 8) {
    float v[8];
    unpack8(hp[k >> 3], v);
    #pragma unroll
    for (int j = 0; j < 8; ++j) {
      #pragma unroll
      for (int o = 0; o < OUTC; ++o) logit[o] += v[j] * sw[(k + j) * OUTC + o];
    }
  }
  float m = logit[0];
  #pragma unroll
  for (int o = 1; o < OUTC; ++o) m = fmaxf(m, logit[o]);
  float s = 0.f;
  #pragma unroll
  for (int o = 0; o < OUTC; ++o) { logit[o] = __expf(logit[o] - m); s += logit[o]; }
  float invs = 1.0f / s;
  #pragma unroll
  for (int o = 0; o < OUTC; ++o) out[(size_t)row * OUTC + o] = logit[o] * invs;
}

extern "C" void kernel_launch(void* const* d_in, const int* in_sizes, int n_in,
                              void* d_out, int out_size, void* d_ws, size_t ws_size,
                              hipStream_t stream) {
  const float* x_c   = (const float*)d_in[0];
  const float* x_t   = (const float*)d_in[1];
  const float* x_p   = (const float*)d_in[2];
  const float* W_col = (const float*)d_in[3];
  const float* b_col = (const float*)d_in[4];
  const float* Wn    = (const float*)d_in[5];
  const float* Wr    = (const float*)d_in[6];
  const float* b_lin = (const float*)d_in[7];
  const float* W_out = (const float*)d_in[8];
  const float* b_out = (const float*)d_in[9];
  const int* e_m_src = (const int*)d_in[10];
  const int* e_m_dst = (const int*)d_in[11];
  const int* e_i_src = (const int*)d_in[12];
  const int* e_i_dst = (const int*)d_in[13];
  float* out = (float*)d_out;

  // ---- workspace carve-out (~171 MB; round-5 footprint + ~0.4 MB weights) ----
  size_t cursor = 0;
  char* base = (char*)d_ws;
  auto alloc = [&](size_t bytes) {
    void* p = base + cursor;
    cursor += (bytes + 255) & ~(size_t)255;
    return p;
  };
  u16* h_t  = (u16*)alloc((size_t)NTV * DD * 2);
  u16* h_cA = (u16*)alloc((size_t)NCV * DD * 2);
  u16* h_cB = (u16*)alloc((size_t)NCV * DD * 2);
  u16* h_pA = (u16*)alloc((size_t)NPV * DD * 2);
  u16* h_pB = (u16*)alloc((size_t)NPV * DD * 2);
  int* pool = (int*)alloc((size_t)TOTE * 4);
  int* cnt  = (int*)alloc((size_t)NTOT * 4);
  int* off  = (int*)alloc((size_t)(NTOT + 1) * 4);
  int* cur  = (int*)alloc((size_t)(NTOT + 1) * 4);
  int* bsum = (int*)alloc(1024 * 4);
  u16* WB2a = (u16*)alloc((size_t)128 * 384 * 2);
  u16* WB2b = (u16*)alloc((size_t)128 * 384 * 2);
  u16* WB1c = (u16*)alloc((size_t)128 * 256 * 2);
  u16* WB1p = (u16*)alloc((size_t)128 * 256 * 2);
  float* bt2a = (float*)alloc(128 * 4);
  float* bt2b = (float*)alloc(128 * 4);
  float* bt1c = (float*)alloc(128 * 4);
  float* bt1p = (float*)alloc(128 * 4);

  // CSR segment bases: seg0 [0,NT): t<-c (makes); seg1 [NT,2NT): t<-p (in);
  // seg2 [2NT,2NT+NC): c<-t (makes); seg3: p<-t (in).
  const int S0 = 0, S1 = NTV, S2 = 2 * NTV, S3 = 2 * NTV + NCV;

  const float* Wn_l[2][4]; const float* Wr_l[2][4]; const float* b_l[2][4];
  for (int l = 0; l < 2; ++l)
    for (int r = 0; r < 4; ++r) {
      Wn_l[l][r] = Wn + (size_t)(l * 4 + r) * DD * DD;
      Wr_l[l][r] = Wr + (size_t)(l * 4 + r) * DD * DD;
      b_l[l][r]  = b_lin + (size_t)(l * 4 + r) * DD;
    }

  int gEM = (EMV + 255) / 256, gEI = (EIV + 255) / 256;

  // ---- weight prep (independent of everything else) ----
  prep_w2<<<192, 256, 0, stream>>>(Wn_l[0][0], Wn_l[0][2], Wr_l[0][0], Wr_l[0][2],
                                   b_l[0][0], b_l[0][2], WB2a, bt2a);
  prep_w2<<<192, 256, 0, stream>>>(Wn_l[1][0], Wn_l[1][2], Wr_l[1][0], Wr_l[1][2],
                                   b_l[1][0], b_l[1][2], WB2b, bt2b);
  prep_w1<<<128, 256, 0, stream>>>(Wn_l[0][1], Wr_l[0][1], b_l[0][1], WB1c, bt1c);
  prep_w1<<<128, 256, 0, stream>>>(Wn_l[0][3], Wr_l[0][3], b_l[0][3], WB1p, bt1p);

  // ---- CSR build ----
  hipMemsetAsync(cnt, 0, (size_t)NTOT * 4, stream);
  count_kernel<<<gEM, 256, 0, stream>>>(e_m_dst, cnt + S0, EMV);
  count_kernel<<<gEI, 256, 0, stream>>>(e_i_dst, cnt + S1, EIV);
  count_kernel<<<gEM, 256, 0, stream>>>(e_m_src, cnt + S2, EMV);
  count_kernel<<<gEI, 256, 0, stream>>>(e_i_src, cnt + S3, EIV);
  int nblk = (NTOT + 1023) / 1024;  // 733
  scan1_kernel<<<nblk, 256, 0, stream>>>(cnt, off, bsum, NTOT);
  scan2_kernel<<<1, 256, 0, stream>>>(bsum, nblk);
  scan3_kernel<<<(NTOT + 1 + 255) / 256, 256, 0, stream>>>(off, bsum, cur, NTOT, TOTE);
  fill_kernel<<<gEM, 256, 0, stream>>>(e_m_dst, e_m_src, cur + S0, pool, EMV);
  fill_kernel<<<gEI, 256, 0, stream>>>(e_i_dst, e_i_src, cur + S1, pool, EIV);
  fill_kernel<<<gEM, 256, 0, stream>>>(e_m_src, e_m_dst, cur + S2, pool, EMV);
  fill_kernel<<<gEI, 256, 0, stream>>>(e_i_src, e_i_dst, cur + S3, pool, EIV);

  // ---- embeds ----
  embed_kernel<<<(NCV * 8 + 255) / 256, 256, 0, stream>>>(
      x_c, W_col + 0 * DD, b_col + 0 * DD, h_cA, NCV);
  embed_kernel<<<(NTV * 8 + 255) / 256, 256, 0, stream>>>(
      x_t, W_col + 1 * DD, b_col + 1 * DD, h_t, NTV);
  embed_kernel<<<(NPV * 8 + 255) / 256, 256, 0, stream>>>(
      x_p, W_col + 2 * DD, b_col + 2 * DD, h_pA, NPV);

  int gT = NTV / 32, gC = NCV / 32, gP = (NPV + 31) / 32;

  // ---- layer 0 ----
  sage_mfma<1><<<gC, 256, 0, stream>>>(h_cA, h_t, off + S2, nullptr, nullptr, pool,
                                       WB1c, bt1c, h_cB, NCV, 1.0f);
  sage_mfma<1><<<gP, 256, 0, stream>>>(h_pA, h_t, off + S3, nullptr, nullptr, pool,
                                       WB1p, bt1p, h_pB, NPV, 1.0f);
  sage_mfma<2><<<gT, 256, 0, stream>>>(h_t, h_cA, off + S0, h_pA, off + S1, pool,
                                       WB2a, bt2a, h_t, NTV, 0.5f);
  // ---- layer 1 (only h_t live downstream) ----
  sage_mfma<2><<<gT, 256, 0, stream>>>(h_t, h_cB, off + S0, h_pB, off + S1, pool,
                                       WB2b, bt2b, h_t, NTV, 0.5f);

  // ---- head ----
  out_softmax<<<(NTV + 255) / 256, 256, 0, stream>>>(h_t, W_out, b_out, out, NTV);
}